// Round 1
// baseline (396.340 us; speedup 1.0000x reference)
//
#include <hip/hip_runtime.h>
#include <stdint.h>

// Problem constants
constexpr int C      = 256;          // channels (in == out)
constexpr int H      = 28, W = 28;
constexpr int HW     = H * W;        // 784
constexpr int NB     = 64;           // batch
constexpr int WORDS  = 4;            // 256 / 64 bits
constexpr int CNT    = NB * HW;      // per-channel reduction count = 50176
constexpr int TOTAL  = NB * C * HW;  // 12,845,056

// ---------------------------------------------------------------------------
// Pack weight signs: w[co][ci][kh][kw] (OIHW) -> wb[co][tap][wd] (u64 bits)
// bit j of word wd = sign(w[co][wd*64+j][tap]) (1 = negative)
// ---------------------------------------------------------------------------
__global__ void pack_w_kernel(const float* __restrict__ w, uint64_t* __restrict__ wb) {
    int t = blockIdx.x * blockDim.x + threadIdx.x;  // (co*9 + tap)*4 + wd
    if (t >= C * 9 * WORDS) return;
    int wd  = t & 3;
    int tap = (t >> 2) % 9;
    int co  = t / 36;
    const float* base = w + ((size_t)co * C + (size_t)wd * 64) * 9 + tap;
    uint64_t bits = 0;
#pragma unroll 8
    for (int j = 0; j < 64; ++j) {
        if (base[(size_t)j * 9] < 0.f) bits |= (1ull << j);
    }
    wb[(size_t)(co * 9 + tap) * WORDS + wd] = bits;
}

// ---------------------------------------------------------------------------
// Pack activation signs: x[n][c][h][w] -> xb[n][p][wd]  (p = h*W+w)
// ---------------------------------------------------------------------------
__global__ void pack_x_kernel(const float* __restrict__ x, uint64_t* __restrict__ xb) {
    int t = blockIdx.x * blockDim.x + threadIdx.x;  // n*HW + p
    if (t >= NB * HW) return;
    int n = t / HW, p = t % HW;
    const float* base = x + (size_t)n * C * HW + p;
    uint64_t* dst = xb + (size_t)t * WORDS;
#pragma unroll
    for (int wd = 0; wd < WORDS; ++wd) {
        uint64_t bits = 0;
#pragma unroll 8
        for (int j = 0; j < 64; ++j) {
            if (base[(size_t)(wd * 64 + j) * HW] < 0.f) bits |= (1ull << j);
        }
        dst[wd] = bits;
    }
}

// ---------------------------------------------------------------------------
// Fused BN(scale/shift) + binarize + pack: y[n][c][p] -> xb[n][p][wd]
// sign(clip(z)) == sign(z), binarize(0)=+1, so only the sign of z matters.
// ---------------------------------------------------------------------------
__global__ void bn_signpack_kernel(const float* __restrict__ y,
                                   const float* __restrict__ scale,
                                   const float* __restrict__ shift,
                                   uint64_t* __restrict__ xb) {
    int t = blockIdx.x * blockDim.x + threadIdx.x;
    if (t >= NB * HW) return;
    int n = t / HW, p = t % HW;
    const float* base = y + (size_t)n * C * HW + p;
    uint64_t* dst = xb + (size_t)t * WORDS;
#pragma unroll
    for (int wd = 0; wd < WORDS; ++wd) {
        uint64_t bits = 0;
#pragma unroll 8
        for (int j = 0; j < 64; ++j) {
            int c = wd * 64 + j;
            float z = base[(size_t)c * HW] * scale[c] + shift[c];
            if (z < 0.f) bits |= (1ull << j);
        }
        dst[wd] = bits;
    }
}

// ---------------------------------------------------------------------------
// Binary conv 3x3 pad=1 via XNOR+popcount. One block per (n, co).
// Stages the whole [HW][WORDS] bit-slice (25 KB) + 36 weight words in LDS.
// dot over a valid tap = 256 - 2*popc(x^w) summed over 4 words.
// Optionally adds residual; accumulates per-channel sum / sumsq (fp64 atomics).
// ---------------------------------------------------------------------------
__launch_bounds__(256)
__global__ void bconv_kernel(const uint64_t* __restrict__ xb,
                             const uint64_t* __restrict__ wb,
                             const float* __restrict__ residual,
                             float* __restrict__ yout,
                             double* __restrict__ sum, double* __restrict__ sumsq,
                             int has_res) {
    __shared__ alignas(16) uint64_t xl[HW * WORDS];  // 25088 B
    __shared__ alignas(16) uint64_t wl[9 * WORDS];   // 288 B
    __shared__ float red[8];

    const int n  = blockIdx.x;
    const int co = blockIdx.y;
    const int t  = threadIdx.x;

    const uint64_t* xsrc = xb + (size_t)n * HW * WORDS;
    for (int i = t; i < HW * WORDS; i += 256) xl[i] = xsrc[i];
    if (t < 36) wl[t] = wb[(size_t)co * 36 + t];
    __syncthreads();

    float s1 = 0.f, s2 = 0.f;
    for (int p = t; p < HW; p += 256) {
        const int oh = p / W, ow = p % W;
        int pop = 0, valid = 0;
#pragma unroll
        for (int kh = 0; kh < 3; ++kh) {
            const int ih = oh + kh - 1;
            if ((unsigned)ih >= (unsigned)H) continue;
#pragma unroll
            for (int kw = 0; kw < 3; ++kw) {
                const int iw = ow + kw - 1;
                if ((unsigned)iw >= (unsigned)W) continue;
                ++valid;
                const uint64_t* xp = &xl[(ih * W + iw) * WORDS];
                const uint64_t* wp = &wl[(kh * 3 + kw) * WORDS];
                pop += __popcll(xp[0] ^ wp[0]) + __popcll(xp[1] ^ wp[1])
                     + __popcll(xp[2] ^ wp[2]) + __popcll(xp[3] ^ wp[3]);
            }
        }
        float y = (float)(valid * 256 - 2 * pop);
        const size_t oidx = ((size_t)n * C + co) * HW + p;
        if (has_res) y += residual[oidx];
        yout[oidx] = y;
        s1 += y;
        s2 += y * y;
    }

    // block reduction (4 waves of 64)
#pragma unroll
    for (int off = 32; off; off >>= 1) {
        s1 += __shfl_down(s1, off);
        s2 += __shfl_down(s2, off);
    }
    const int wave = t >> 6, lane = t & 63;
    if (lane == 0) { red[wave] = s1; red[wave + 4] = s2; }
    __syncthreads();
    if (t == 0) {
        float a = red[0] + red[1] + red[2] + red[3];
        float b = red[4] + red[5] + red[6] + red[7];
        atomicAdd(&sum[co], (double)a);
        atomicAdd(&sumsq[co], (double)b);
    }
}

// ---------------------------------------------------------------------------
// BN stats -> per-channel scale/shift (fp64 internally)
// ---------------------------------------------------------------------------
__global__ void finalize_kernel(const double* __restrict__ sum,
                                const double* __restrict__ sumsq,
                                const float* __restrict__ gamma,
                                const float* __restrict__ beta,
                                float* __restrict__ scale,
                                float* __restrict__ shift) {
    int c = threadIdx.x;  // 256 threads
    double mean = sum[c] / (double)CNT;
    double var  = sumsq[c] / (double)CNT - mean * mean;
    double inv  = 1.0 / sqrt(var + 1e-5);
    float sc = (float)inv * gamma[c];
    scale[c] = sc;
    shift[c] = beta[c] - (float)(mean * inv) * gamma[c];
}

// ---------------------------------------------------------------------------
// Final: out = clip(z*scale[c] + shift[c], -1, 1)
// ---------------------------------------------------------------------------
__global__ void bn_clip_kernel(const float* __restrict__ z,
                               const float* __restrict__ scale,
                               const float* __restrict__ shift,
                               float* __restrict__ out, int total) {
    for (int i = blockIdx.x * blockDim.x + threadIdx.x; i < total;
         i += gridDim.x * blockDim.x) {
        int c = (i / HW) & (C - 1);
        float v = z[i] * scale[c] + shift[c];
        out[i] = fminf(1.f, fmaxf(-1.f, v));
    }
}

// ---------------------------------------------------------------------------
extern "C" void kernel_launch(void* const* d_in, const int* in_sizes, int n_in,
                              void* d_out, int out_size, void* d_ws, size_t ws_size,
                              hipStream_t stream) {
    const float* x  = (const float*)d_in[0];
    const float* w1 = (const float*)d_in[1];
    const float* w2 = (const float*)d_in[2];
    const float* g1 = (const float*)d_in[3];
    const float* b1 = (const float*)d_in[4];
    const float* g2 = (const float*)d_in[5];
    const float* b2 = (const float*)d_in[6];
    float* out = (float*)d_out;

    char* ws = (char*)d_ws;
    size_t off = 0;
    float* z2 = (float*)(ws + off);          off += (size_t)TOTAL * 4;        // 51.4 MB
    uint64_t* xb1 = (uint64_t*)(ws + off);   off += (size_t)NB * HW * WORDS * 8;  // 1.6 MB
    uint64_t* xb2 = (uint64_t*)(ws + off);   off += (size_t)NB * HW * WORDS * 8;
    uint64_t* wb1 = (uint64_t*)(ws + off);   off += (size_t)C * 9 * WORDS * 8;    // 73 KB
    uint64_t* wb2 = (uint64_t*)(ws + off);   off += (size_t)C * 9 * WORDS * 8;
    double* stats = (double*)(ws + off);     off += 4 * 256 * 8;
    double* sum1 = stats, *sumsq1 = stats + 256, *sum2 = stats + 512, *sumsq2 = stats + 768;
    float* coefs = (float*)(ws + off);       off += 4 * 256 * 4;
    float* scale1 = coefs, *shift1 = coefs + 256, *scale2 = coefs + 512, *shift2 = coefs + 768;

    // zero the fp64 stat accumulators (ws is re-poisoned before every launch)
    hipMemsetAsync(stats, 0, 4 * 256 * 8, stream);

    // pack weights + input signs
    pack_w_kernel<<<(C * 9 * WORDS + 255) / 256, 256, 0, stream>>>(w1, wb1);
    pack_w_kernel<<<(C * 9 * WORDS + 255) / 256, 256, 0, stream>>>(w2, wb2);
    pack_x_kernel<<<(NB * HW + 255) / 256, 256, 0, stream>>>(x, xb1);

    dim3 cgrid(NB, C);
    // conv1: y1 -> d_out (scratch), fused BN1 stats
    bconv_kernel<<<cgrid, 256, 0, stream>>>(xb1, wb1, nullptr, out, sum1, sumsq1, 0);
    finalize_kernel<<<1, 256, 0, stream>>>(sum1, sumsq1, g1, b1, scale1, shift1);
    // BN1 + hardtanh + binarize collapse to sign(BN1) -> bit-pack
    bn_signpack_kernel<<<(NB * HW + 255) / 256, 256, 0, stream>>>(out, scale1, shift1, xb2);
    // conv2 + residual, fused BN2 stats, z2 -> ws
    bconv_kernel<<<cgrid, 256, 0, stream>>>(xb2, wb2, x, z2, sum2, sumsq2, 1);
    finalize_kernel<<<1, 256, 0, stream>>>(sum2, sumsq2, g2, b2, scale2, shift2);
    // BN2 + hardtanh -> out
    bn_clip_kernel<<<4096, 256, 0, stream>>>(z2, scale2, shift2, out, TOTAL);
}